// Round 1
// baseline (444.085 us; speedup 1.0000x reference)
//
#include <hip/hip_runtime.h>
#include <hip/hip_bf16.h>

#define T_TRIP 500000
#define NP     100000

typedef float f32x4 __attribute__((ext_vector_type(4)));
typedef __bf16 bf16x8 __attribute__((ext_vector_type(8)));
typedef unsigned short u16;

__device__ __forceinline__ u16 f2bf(float f) {
  union { float f; unsigned u; } v; v.f = f;
  unsigned r = v.u + 0x7fffu + ((v.u >> 16) & 1u);
  return (u16)(r >> 16);
}

__device__ __forceinline__ ushort4 cvt4(float4 v) {
  ushort4 o; o.x = f2bf(v.x); o.y = f2bf(v.y); o.z = f2bf(v.z); o.w = f2bf(v.w);
  return o;
}

#define MFMA16(a, b, c) __builtin_amdgcn_mfma_f32_16x16x32_bf16((a), (b), (c), 0, 0, 0)

// ---- ws layout (u16 element offsets) ----
#define PSI_W1T_OFF 0           // [128 n][416 k]  (k >= 388 zero-padded)
#define PSI_W2T_OFF 53248       // [128 n][128 k]
#define PHI_W1T_OFF 69632       // [128 n][256 k]
#define PHI_W2T_OFF 102400      // [128 n][128 k]
#define WS_U16_TOTAL 118784

__global__ void k_prep(const float* __restrict__ psi_w1, const float* __restrict__ psi_w2,
                       const float* __restrict__ phi_w1, const float* __restrict__ phi_w2,
                       u16* __restrict__ ws) {
  int i = blockIdx.x * 256 + threadIdx.x;
  if (i < 128 * 416) {
    int n = i / 416, k = i % 416;
    ws[PSI_W1T_OFF + i] = f2bf(k < 388 ? psi_w1[k * 128 + n] : 0.f);
    return;
  }
  i -= 128 * 416;
  if (i < 128 * 128) {
    int n = i / 128, k = i % 128;
    ws[PSI_W2T_OFF + i] = f2bf(psi_w2[k * 128 + n]);
    return;
  }
  i -= 128 * 128;
  if (i < 128 * 256) {
    int n = i / 256, k = i % 256;
    ws[PHI_W1T_OFF + i] = f2bf(phi_w1[k * 128 + n]);
    return;
  }
  i -= 128 * 256;
  if (i < 128 * 128) {
    int n = i / 128, k = i % 128;
    ws[PHI_W2T_OFF + i] = f2bf(phi_w2[k * 128 + n]);
  }
}

// ---------------- triplet kernel ----------------
// 64 triplets x 128 outputs per block; 4 waves, each wave = 64 rows x 32 cols.
// GEMM1: K=416 (388 padded). GEMM2: K=128. Scatter-add into agg (= d_out).
#define XSTR 424   // lds stride for x tile (bf16 units), 848B = 53*16
#define HSTR 136   // lds stride for hidden tile, 272B = 17*16

__global__ __launch_bounds__(256, 2) void k_triplet(
    const float* __restrict__ h_pair,
    const int* __restrict__ ivu, const int* __restrict__ iuw, const int* __restrict__ ivw,
    const float* __restrict__ geom,
    const u16* __restrict__ W1T, const u16* __restrict__ W2T,
    const float* __restrict__ b1, const float* __restrict__ b2,
    float* __restrict__ agg) {
  __shared__ __align__(16) u16 xl[64 * XSTR];
  __shared__ __align__(16) u16 hl[64 * HSTR];
  __shared__ int svw[64];

  const int tid = threadIdx.x;
  const int t0 = blockIdx.x * 64;

  // ---- stage gathered x = [h_vu | h_uw | h_vw | geom | pad] as bf16 ----
  {
    const int row = tid >> 2, q = tid & 3;
    const int t = t0 + row;
    const int tc = (t < T_TRIP) ? t : (T_TRIP - 1);
    if (q == 0) svw[row] = (t < T_TRIP) ? ivw[tc] : -1;
    int idx[3];
    idx[0] = ivu[tc]; idx[1] = iuw[tc]; idx[2] = ivw[tc];
#pragma unroll
    for (int s = 0; s < 3; ++s) {
      const float4* src = reinterpret_cast<const float4*>(h_pair + (size_t)idx[s] * 128 + q * 32);
      u16* dst = &xl[row * XSTR + s * 128 + q * 32];
#pragma unroll
      for (int i = 0; i < 8; ++i) {
        *reinterpret_cast<ushort4*>(dst + i * 4) = cvt4(src[i]);
      }
    }
  }
  if (tid < 64) {
    const int t = t0 + tid;
    const int tc = (t < T_TRIP) ? t : (T_TRIP - 1);
    const float4 g = reinterpret_cast<const float4*>(geom)[tc];
    u16* dst = &xl[tid * XSTR + 384];
    *reinterpret_cast<ushort4*>(dst) = cvt4(g);
    ushort4 z = {0, 0, 0, 0};
#pragma unroll
    for (int i = 1; i < 8; ++i) *reinterpret_cast<ushort4*>(dst + i * 4) = z;
  }
  __syncthreads();

  const int w = tid >> 6;         // wave 0..3 -> cols [w*32, w*32+32)
  const int l = tid & 63;
  const int lr = l & 15;
  const int lk = (l >> 4) << 3;   // 0,8,16,24
  const int n0 = w * 32 + lr;
  const int rowh = (l >> 4) << 2; // C/D row base: (lane>>4)*4

  // ---- GEMM1: [64 x 416] @ [416 x 128] ----
  f32x4 acc[4][2] = {};
#pragma unroll 1
  for (int ks = 0; ks < 13; ++ks) {
    const int k0 = ks * 32;
    bf16x8 a[4], b[2];
#pragma unroll
    for (int rt = 0; rt < 4; ++rt)
      a[rt] = *reinterpret_cast<const bf16x8*>(&xl[(rt * 16 + lr) * XSTR + k0 + lk]);
#pragma unroll
    for (int ct = 0; ct < 2; ++ct)
      b[ct] = *reinterpret_cast<const bf16x8*>(&W1T[(size_t)(n0 + ct * 16) * 416 + k0 + lk]);
#pragma unroll
    for (int rt = 0; rt < 4; ++rt)
#pragma unroll
      for (int ct = 0; ct < 2; ++ct)
        acc[rt][ct] = MFMA16(a[rt], b[ct], acc[rt][ct]);
  }

  // ---- bias + silu -> hl (bf16) ----
  {
    const float b1v0 = b1[n0], b1v1 = b1[n0 + 16];
#pragma unroll
    for (int rt = 0; rt < 4; ++rt)
#pragma unroll
      for (int ct = 0; ct < 2; ++ct) {
        const float bb = ct ? b1v1 : b1v0;
#pragma unroll
        for (int j = 0; j < 4; ++j) {
          float v = acc[rt][ct][j] + bb;
          v = v / (1.f + __expf(-v));   // silu
          hl[(rt * 16 + rowh + j) * HSTR + n0 + ct * 16] = f2bf(v);
        }
      }
  }
  __syncthreads();

  // ---- GEMM2: [64 x 128] @ [128 x 128] ----
  f32x4 acc2[4][2] = {};
#pragma unroll
  for (int ks = 0; ks < 4; ++ks) {
    const int k0 = ks * 32;
    bf16x8 a[4], b[2];
#pragma unroll
    for (int rt = 0; rt < 4; ++rt)
      a[rt] = *reinterpret_cast<const bf16x8*>(&hl[(rt * 16 + lr) * HSTR + k0 + lk]);
#pragma unroll
    for (int ct = 0; ct < 2; ++ct)
      b[ct] = *reinterpret_cast<const bf16x8*>(&W2T[(size_t)(n0 + ct * 16) * 128 + k0 + lk]);
#pragma unroll
    for (int rt = 0; rt < 4; ++rt)
#pragma unroll
      for (int ct = 0; ct < 2; ++ct)
        acc2[rt][ct] = MFMA16(a[rt], b[ct], acc2[rt][ct]);
  }

  // ---- bias + scatter-add ----
  {
    const float b2v0 = b2[n0], b2v1 = b2[n0 + 16];
#pragma unroll
    for (int rt = 0; rt < 4; ++rt)
#pragma unroll
      for (int j = 0; j < 4; ++j) {
        const int row = rt * 16 + rowh + j;
        const int dst = svw[row];
        if (dst >= 0) {
          unsafeAtomicAdd(&agg[(size_t)dst * 128 + n0], acc2[rt][0][j] + b2v0);
          unsafeAtomicAdd(&agg[(size_t)dst * 128 + n0 + 16], acc2[rt][1][j] + b2v1);
        }
      }
  }
}

// ---------------- pair kernel ----------------
// out = h_pair + MLP_phi([h_pair | agg]);  agg lives in d_out on entry.
#define X2STR 264  // 528B = 33*16

__global__ __launch_bounds__(256, 2) void k_pair(
    const float* __restrict__ h_pair,
    const u16* __restrict__ W1T, const u16* __restrict__ W2T,
    const float* __restrict__ b1, const float* __restrict__ b2,
    float* __restrict__ out) {
  __shared__ __align__(16) u16 xl[64 * X2STR];
  __shared__ __align__(16) u16 hl[64 * HSTR];

  const int tid = threadIdx.x;
  const int r0 = blockIdx.x * 64;

  // ---- stage [h_pair | agg] as bf16 ----
  {
    const int row = tid >> 2, q = tid & 3;
    const int r = r0 + row;
    const int rc = (r < NP) ? r : (NP - 1);
    const float4* s1 = reinterpret_cast<const float4*>(h_pair + (size_t)rc * 128 + q * 32);
    const float4* s2 = reinterpret_cast<const float4*>(out + (size_t)rc * 128 + q * 32);
    u16* d1 = &xl[row * X2STR + q * 32];
    u16* d2 = &xl[row * X2STR + 128 + q * 32];
#pragma unroll
    for (int i = 0; i < 8; ++i) {
      *reinterpret_cast<ushort4*>(d1 + i * 4) = cvt4(s1[i]);
      *reinterpret_cast<ushort4*>(d2 + i * 4) = cvt4(s2[i]);
    }
  }
  __syncthreads();

  const int w = tid >> 6;
  const int l = tid & 63;
  const int lr = l & 15;
  const int lk = (l >> 4) << 3;
  const int n0 = w * 32 + lr;
  const int rowh = (l >> 4) << 2;

  // ---- GEMM1: [64 x 256] @ [256 x 128] ----
  f32x4 acc[4][2] = {};
#pragma unroll 1
  for (int ks = 0; ks < 8; ++ks) {
    const int k0 = ks * 32;
    bf16x8 a[4], b[2];
#pragma unroll
    for (int rt = 0; rt < 4; ++rt)
      a[rt] = *reinterpret_cast<const bf16x8*>(&xl[(rt * 16 + lr) * X2STR + k0 + lk]);
#pragma unroll
    for (int ct = 0; ct < 2; ++ct)
      b[ct] = *reinterpret_cast<const bf16x8*>(&W1T[(size_t)(n0 + ct * 16) * 256 + k0 + lk]);
#pragma unroll
    for (int rt = 0; rt < 4; ++rt)
#pragma unroll
      for (int ct = 0; ct < 2; ++ct)
        acc[rt][ct] = MFMA16(a[rt], b[ct], acc[rt][ct]);
  }

  {
    const float b1v0 = b1[n0], b1v1 = b1[n0 + 16];
#pragma unroll
    for (int rt = 0; rt < 4; ++rt)
#pragma unroll
      for (int ct = 0; ct < 2; ++ct) {
        const float bb = ct ? b1v1 : b1v0;
#pragma unroll
        for (int j = 0; j < 4; ++j) {
          float v = acc[rt][ct][j] + bb;
          v = v / (1.f + __expf(-v));
          hl[(rt * 16 + rowh + j) * HSTR + n0 + ct * 16] = f2bf(v);
        }
      }
  }
  __syncthreads();

  // ---- GEMM2: [64 x 128] @ [128 x 128] ----
  f32x4 acc2[4][2] = {};
#pragma unroll
  for (int ks = 0; ks < 4; ++ks) {
    const int k0 = ks * 32;
    bf16x8 a[4], b[2];
#pragma unroll
    for (int rt = 0; rt < 4; ++rt)
      a[rt] = *reinterpret_cast<const bf16x8*>(&hl[(rt * 16 + lr) * HSTR + k0 + lk]);
#pragma unroll
    for (int ct = 0; ct < 2; ++ct)
      b[ct] = *reinterpret_cast<const bf16x8*>(&W2T[(size_t)(n0 + ct * 16) * 128 + k0 + lk]);
#pragma unroll
    for (int rt = 0; rt < 4; ++rt)
#pragma unroll
      for (int ct = 0; ct < 2; ++ct)
        acc2[rt][ct] = MFMA16(a[rt], b[ct], acc2[rt][ct]);
  }

  // ---- residual epilogue (f32), overwrite agg rows with final output ----
  {
    const float b2v0 = b2[n0], b2v1 = b2[n0 + 16];
#pragma unroll
    for (int rt = 0; rt < 4; ++rt)
#pragma unroll
      for (int j = 0; j < 4; ++j) {
        const int row = rt * 16 + rowh + j;
        const int r = r0 + row;
        if (r < NP) {
          out[(size_t)r * 128 + n0]      = h_pair[(size_t)r * 128 + n0]      + acc2[rt][0][j] + b2v0;
          out[(size_t)r * 128 + n0 + 16] = h_pair[(size_t)r * 128 + n0 + 16] + acc2[rt][1][j] + b2v1;
        }
      }
  }
}

extern "C" void kernel_launch(void* const* d_in, const int* in_sizes, int n_in,
                              void* d_out, int out_size, void* d_ws, size_t ws_size,
                              hipStream_t stream) {
  const float* h_pair = (const float*)d_in[0];
  const int* ivu = (const int*)d_in[1];
  const int* iuw = (const int*)d_in[2];
  const int* ivw = (const int*)d_in[3];
  const float* geom = (const float*)d_in[4];
  const float* psi_w1 = (const float*)d_in[5];
  const float* psi_b1 = (const float*)d_in[6];
  const float* psi_w2 = (const float*)d_in[7];
  const float* psi_b2 = (const float*)d_in[8];
  const float* phi_w1 = (const float*)d_in[9];
  const float* phi_b1 = (const float*)d_in[10];
  const float* phi_w2 = (const float*)d_in[11];
  const float* phi_b2 = (const float*)d_in[12];

  float* out = (float*)d_out;
  u16* ws = (u16*)d_ws;

  // agg buffer lives in d_out during phase 1; zero it.
  hipMemsetAsync(d_out, 0, (size_t)out_size * sizeof(float), stream);

  // weight conversion to bf16 transposed layouts
  k_prep<<<(WS_U16_TOTAL + 255) / 256, 256, 0, stream>>>(psi_w1, psi_w2, phi_w1, phi_w2, ws);

  // triplet MLP + scatter-add
  k_triplet<<<(T_TRIP + 63) / 64, 256, 0, stream>>>(
      h_pair, ivu, iuw, ivw, geom,
      ws + PSI_W1T_OFF, ws + PSI_W2T_OFF, psi_b1, psi_b2, out);

  // pair MLP + residual
  k_pair<<<(NP + 63) / 64, 256, 0, stream>>>(
      h_pair, ws + PHI_W1T_OFF, ws + PHI_W2T_OFF, phi_b1, phi_b2, out);
}

// Round 2
// 279.839 us; speedup vs baseline: 1.5869x; 1.5869x over previous
//
#include <hip/hip_runtime.h>
#include <hip/hip_bf16.h>

#define T_TRIP 500000
#define NP     100000
#define NTILES 7813   // ceil(T_TRIP/64)

typedef float f32x4 __attribute__((ext_vector_type(4)));
typedef __bf16 bf16x8 __attribute__((ext_vector_type(8)));
typedef unsigned short u16;
typedef unsigned short u16x8 __attribute__((ext_vector_type(8)));

__device__ __forceinline__ u16 f2bf(float f) {
  union { float f; unsigned u; } v; v.f = f;
  unsigned r = v.u + 0x7fffu + ((v.u >> 16) & 1u);
  return (u16)(r >> 16);
}

__device__ __forceinline__ ushort4 cvt4(float4 v) {
  ushort4 o; o.x = f2bf(v.x); o.y = f2bf(v.y); o.z = f2bf(v.z); o.w = f2bf(v.w);
  return o;
}

#define MFMA16(a, b, c) __builtin_amdgcn_mfma_f32_16x16x32_bf16((a), (b), (c), 0, 0, 0)

#define WAITVM(N) asm volatile("s_waitcnt vmcnt(" #N ")" ::: "memory")
#define LGKM0()   asm volatile("s_waitcnt lgkmcnt(0)" ::: "memory")

__device__ __forceinline__ void barrier_raw() {
  asm volatile("" ::: "memory");
  __builtin_amdgcn_s_barrier();
  asm volatile("" ::: "memory");
  __builtin_amdgcn_sched_barrier(0);
}

__device__ __forceinline__ void gload_lds16(const u16* g, u16* l) {
  __builtin_amdgcn_global_load_lds((const __attribute__((address_space(1))) void*)g,
                                   (__attribute__((address_space(3))) void*)l, 16, 0, 0);
}
__device__ __forceinline__ void gload_lds4(const int* g, int* l) {
  __builtin_amdgcn_global_load_lds((const __attribute__((address_space(1))) void*)g,
                                   (__attribute__((address_space(3))) void*)l, 4, 0, 0);
}

// =================== FAST-PATH ws layout (u16 element offsets) ===================
#define FP_W1A   0u         // [128 n][128 k] bf16  (psi_w1 rows   0..127)
#define FP_W1B   16384u     // [128 n][128 k]       (psi_w1 rows 128..255)
#define FP_W1C   32768u     // [128 n][128 k]       (psi_w1 rows 256..383)
#define FP_W2    49152u     // [128 n][128 k]
#define FP_PW1   65536u     // [128 n][256 k]
#define FP_PW2   98304u     // [128 n][128 k]
#define FP_W1D   114688u    // [4 k][128 n] f32 (512 floats = 1024 u16)
#define FP_H     131072u    // h_pair as bf16 [NP][128]
#define FP_AGG   12931072u  // agg as bf16 [NP][128]
#define WS_NEED_BYTES 51462144ull

#define HSTR  136   // hidden tile stride (u16), 272B = 17*16
#define GSTR  520   // XB group stride (u16), 1040B = 65*16
#define X2STR 264   // pair-input tile stride (u16), 528B = 33*16

// ---------------- fast prep: weights -> bf16 transposed + W1d f32 ----------------
__global__ void k_prep_fast(const float* __restrict__ psi_w1, const float* __restrict__ psi_w2,
                            const float* __restrict__ phi_w1, const float* __restrict__ phi_w2,
                            u16* __restrict__ ws) {
  int i = blockIdx.x * 256 + threadIdx.x;
  if (i < 49152) {                       // three W1 slices
    int s = i / 16384, r = i % 16384;
    int n = r / 128, k = r % 128;
    ws[FP_W1A + i] = f2bf(psi_w1[(s * 128 + k) * 128 + n]);
    return;
  }
  i -= 49152;
  if (i < 16384) {
    int n = i / 128, k = i % 128;
    ws[FP_W2 + i] = f2bf(psi_w2[k * 128 + n]);
    return;
  }
  i -= 16384;
  if (i < 32768) {
    int n = i / 256, k = i % 256;
    ws[FP_PW1 + i] = f2bf(phi_w1[k * 128 + n]);
    return;
  }
  i -= 32768;
  if (i < 16384) {
    int n = i / 128, k = i % 128;
    ws[FP_PW2 + i] = f2bf(phi_w2[k * 128 + n]);
    return;
  }
  i -= 16384;
  if (i < 512) {                          // geom weights, exact f32, [k][n]
    int k = i / 128, n = i % 128;
    reinterpret_cast<float*>(ws + FP_W1D)[i] = psi_w1[(384 + k) * 128 + n];
  }
}

// ---------------- h_pair -> bf16, zero agg ----------------
__global__ void k_hconv(const float* __restrict__ h, u16* __restrict__ H, u16* __restrict__ AGG) {
  const size_t i = (size_t)(blockIdx.x * 256 + threadIdx.x) * 8;
  float4 v0 = *reinterpret_cast<const float4*>(h + i);
  float4 v1 = *reinterpret_cast<const float4*>(h + i + 4);
  *reinterpret_cast<ushort4*>(H + i)     = cvt4(v0);
  *reinterpret_cast<ushort4*>(H + i + 4) = cvt4(v1);
  ushort4 z = {0, 0, 0, 0};
  *reinterpret_cast<ushort4*>(AGG + i)     = z;
  *reinterpret_cast<ushort4*>(AGG + i + 4) = z;
}

// ---------------- fast triplet kernel ----------------
// Persistent blocks, 64 triplets/tile, 4 waves x (64 rows x 32 cols).
// GEMM1 split into 3 source GEMMs (K=128 each) ping-ponged across XB[2],
// staged via global_load_lds x16 with XOR chunk swizzle; geom term in f32 VALU.
// Counted vmcnt, raw barriers. Scatter via packed bf16 atomics.
__global__ __launch_bounds__(256, 3) void k_triplet_fast(
    const u16* __restrict__ H,
    const int* __restrict__ ivu, const int* __restrict__ iuw, const int* __restrict__ ivw,
    const float* __restrict__ geom,
    const u16* __restrict__ W1A, const u16* __restrict__ W1B, const u16* __restrict__ W1C,
    const float* __restrict__ w1dF, const u16* __restrict__ W2T,
    const float* __restrict__ b1, const float* __restrict__ b2,
    u16* __restrict__ AGG) {
  __shared__ __align__(16) u16 XB[2][16 * GSTR];     // 33280 B
  __shared__ __align__(16) u16 hl[64 * HSTR];        // 17408 B
  __shared__ __align__(16) float geomF[2][64][4];    //  2048 B
  __shared__ int svw[2][64];                         //   512 B

  const int tid = threadIdx.x;
  const int w = tid >> 6, l = tid & 63;
  const int lr = l & 15;
  const int lk = (l >> 4) << 3;
  const int n0 = w * 32 + lr;
  const int rowh = (l >> 4) << 2;
  const int srow = l >> 4;                               // staging slot in group
  const int schunk = (l & 15) ^ ((l >> 4) << 1);         // XOR-swizzled source chunk

  // hoisted constants
  bf16x8 w2f[4][2];
#pragma unroll
  for (int ks = 0; ks < 4; ++ks)
#pragma unroll
    for (int ct = 0; ct < 2; ++ct)
      w2f[ks][ct] = *reinterpret_cast<const bf16x8*>(&W2T[(size_t)(n0 + ct * 16) * 128 + ks * 32 + lk]);
  const float b1v[2] = {b1[n0], b1[n0 + 16]};
  const float b2v[2] = {b2[n0], b2[n0 + 16]};
  float w1dv[4][2];
#pragma unroll
  for (int k = 0; k < 4; ++k) {
    w1dv[k][0] = w1dF[k * 128 + n0];
    w1dv[k][1] = w1dF[k * 128 + n0 + 16];
  }

  auto stage_src = [&](const int* idxa, int tile, int buf) {
    const int t0 = tile * 64;
#pragma unroll
    for (int q = 0; q < 4; ++q) {
      const int g = w * 4 + q;
      int t = t0 + g * 4 + srow; t = (t < T_TRIP) ? t : (T_TRIP - 1);
      const int idx = idxa[t];
      gload_lds16(H + (size_t)idx * 128 + schunk * 8, &XB[buf][g * GSTR]);
    }
  };

  auto stage_aux = [&](int tile, int tb) {
    const int t0 = tile * 64;
    int t = t0 + l; t = (t < T_TRIP) ? t : (T_TRIP - 1);
    if (w == 0) {
      gload_lds16(reinterpret_cast<const u16*>(geom + (size_t)t * 4),
                  reinterpret_cast<u16*>(&geomF[tb][0][0]));
    } else if (w == 1) {
      gload_lds4(ivw + t, &svw[tb][0]);
    }
  };

  auto gemm_src = [&](const u16* WT, int buf, f32x4 (&acc)[4][2]) {
#pragma unroll
    for (int ks = 0; ks < 4; ++ks) {
      bf16x8 a[4], b[2];
#pragma unroll
      for (int rt = 0; rt < 4; ++rt) {
        const int r = rt * 16 + lr;
        const int g = r >> 2, s = r & 3;
        const int j = ks * 4 + (l >> 4);
        a[rt] = *reinterpret_cast<const bf16x8*>(&XB[buf][g * GSTR + s * 128 + ((j ^ (s << 1)) << 3)]);
      }
#pragma unroll
      for (int ct = 0; ct < 2; ++ct)
        b[ct] = *reinterpret_cast<const bf16x8*>(&WT[(size_t)(n0 + ct * 16) * 128 + ks * 32 + lk]);
#pragma unroll
      for (int rt = 0; rt < 4; ++rt)
#pragma unroll
        for (int ct = 0; ct < 2; ++ct)
          acc[rt][ct] = MFMA16(a[rt], b[ct], acc[rt][ct]);
    }
  };

  int pb = 0, tb = 0;
  int tt = blockIdx.x;
  // prologue: stage s0 of first tile
  stage_src(ivu, tt, 0);

  for (; tt < NTILES; tt += gridDim.x) {
    const int t0 = tt * 64;
    int ttn = tt + gridDim.x; if (ttn >= NTILES) ttn = tt;

    // stage s1 + aux for this tile
    stage_src(iuw, tt, pb ^ 1);
    stage_aux(tt, tb);
    WAITVM(4);          // s0 staged (newest 4 = s1 [+aux])
    barrier_raw();

    f32x4 acc[4][2] = {};
    gemm_src(W1A, pb, acc);          // source 0
    barrier_raw();                   // WAR: XB[pb] free

    stage_src(ivw, tt, pb);          // s2 -> XB[pb]
    WAITVM(4);                       // s1 (+aux) staged
    barrier_raw();

    gemm_src(W1B, pb ^ 1, acc);      // source 1

    WAITVM(0);                       // s2 staged
    barrier_raw();

    stage_src(ivu, ttn, pb ^ 1);     // next tile s0 -> XB[pb^1] (reads done)
    gemm_src(W1C, pb, acc);          // source 2

    // geom contribution (exact f32)
#pragma unroll
    for (int rt = 0; rt < 4; ++rt)
#pragma unroll
      for (int j = 0; j < 4; ++j) {
        const float4 g4 = *reinterpret_cast<const float4*>(&geomF[tb][rt * 16 + rowh + j][0]);
#pragma unroll
        for (int ct = 0; ct < 2; ++ct)
          acc[rt][ct][j] += g4.x * w1dv[0][ct] + g4.y * w1dv[1][ct] +
                            g4.z * w1dv[2][ct] + g4.w * w1dv[3][ct];
      }

    // bias + silu -> hl (bf16)
#pragma unroll
    for (int rt = 0; rt < 4; ++rt)
#pragma unroll
      for (int ct = 0; ct < 2; ++ct) {
        const float bb = b1v[ct];
#pragma unroll
        for (int j = 0; j < 4; ++j) {
          float v = acc[rt][ct][j] + bb;
          v = v / (1.f + __expf(-v));
          hl[(rt * 16 + rowh + j) * HSTR + n0 + ct * 16] = f2bf(v);
        }
      }
    LGKM0();
    barrier_raw();

    // GEMM2 with hoisted W2 fragments
    f32x4 acc2[4][2] = {};
#pragma unroll
    for (int ks = 0; ks < 4; ++ks) {
      bf16x8 a[4];
#pragma unroll
      for (int rt = 0; rt < 4; ++rt)
        a[rt] = *reinterpret_cast<const bf16x8*>(&hl[(rt * 16 + lr) * HSTR + ks * 32 + lk]);
#pragma unroll
      for (int rt = 0; rt < 4; ++rt)
#pragma unroll
        for (int ct = 0; ct < 2; ++ct)
          acc2[rt][ct] = MFMA16(a[rt], w2f[ks][ct], acc2[rt][ct]);
    }

    // scatter: pack adjacent columns via shfl, pk bf16 atomics
#pragma unroll
    for (int rt = 0; rt < 4; ++rt) {
      const int4 d4 = *reinterpret_cast<const int4*>(&svw[tb][rt * 16 + rowh]);
#pragma unroll
      for (int j = 0; j < 4; ++j) {
        const int dst = (&d4.x)[j];
        const int trow = t0 + rt * 16 + rowh + j;
        float v0 = acc2[rt][0][j] + b2v[0];
        float v1 = acc2[rt][1][j] + b2v[1];
        float x0 = __shfl_xor(v0, 1, 64);
        float x1 = __shfl_xor(v1, 1, 64);
        const bool even = (l & 1) == 0;
        float lo = even ? v0 : x1;
        float hi = even ? x0 : v1;
        const int col = even ? n0 : (n0 + 15);
        if (trow < T_TRIP) {
          u16* p = AGG + (size_t)dst * 128 + col;
          unsigned pk = ((unsigned)f2bf(hi) << 16) | (unsigned)f2bf(lo);
          asm volatile("global_atomic_pk_add_bf16 %0, %1, off" :: "v"(p), "v"(pk) : "memory");
        }
      }
    }
    pb ^= 1; tb ^= 1;
  }
  WAITVM(0);   // don't end with LDS-DMA in flight
}

// ---------------- fast pair kernel ----------------
__global__ __launch_bounds__(256, 3) void k_pair_fast(
    const float* __restrict__ h_pair, const u16* __restrict__ H, const u16* __restrict__ AGG,
    const u16* __restrict__ PW1T, const u16* __restrict__ PW2T,
    const float* __restrict__ b1, const float* __restrict__ b2,
    float* __restrict__ out) {
  __shared__ __align__(16) u16 xl[64 * X2STR];
  __shared__ __align__(16) u16 hl[64 * HSTR];

  const int tid = threadIdx.x;
  const int r0 = blockIdx.x * 64;

  {
    const int row = tid >> 2, q = tid & 3;
    int rc = r0 + row; rc = (rc < NP) ? rc : (NP - 1);
    const u16x8* sh = reinterpret_cast<const u16x8*>(H + (size_t)rc * 128 + q * 32);
    const u16x8* sa = reinterpret_cast<const u16x8*>(AGG + (size_t)rc * 128 + q * 32);
    u16x8* d1 = reinterpret_cast<u16x8*>(&xl[row * X2STR + q * 32]);
    u16x8* d2 = reinterpret_cast<u16x8*>(&xl[row * X2STR + 128 + q * 32]);
#pragma unroll
    for (int i = 0; i < 4; ++i) { d1[i] = sh[i]; d2[i] = sa[i]; }
  }
  __syncthreads();

  const int w = tid >> 6, l = tid & 63;
  const int lr = l & 15;
  const int lk = (l >> 4) << 3;
  const int n0 = w * 32 + lr;
  const int rowh = (l >> 4) << 2;

  f32x4 acc[4][2] = {};
#pragma unroll 1
  for (int ks = 0; ks < 8; ++ks) {
    const int k0 = ks * 32;
    bf16x8 a[4], b[2];
#pragma unroll
    for (int rt = 0; rt < 4; ++rt)
      a[rt] = *reinterpret_cast<const bf16x8*>(&xl[(rt * 16 + lr) * X2STR + k0 + lk]);
#pragma unroll
    for (int ct = 0; ct < 2; ++ct)
      b[ct] = *reinterpret_cast<const bf16x8*>(&PW1T[(size_t)(n0 + ct * 16) * 256 + k0 + lk]);
#pragma unroll
    for (int rt = 0; rt < 4; ++rt)
#pragma unroll
      for (int ct = 0; ct < 2; ++ct)
        acc[rt][ct] = MFMA16(a[rt], b[ct], acc[rt][ct]);
  }

  {
    const float b1v0 = b1[n0], b1v1 = b1[n0 + 16];
#pragma unroll
    for (int rt = 0; rt < 4; ++rt)
#pragma unroll
      for (int ct = 0; ct < 2; ++ct) {
        const float bb = ct ? b1v1 : b1v0;
#pragma unroll
        for (int j = 0; j < 4; ++j) {
          float v = acc[rt][ct][j] + bb;
          v = v / (1.f + __expf(-v));
          hl[(rt * 16 + rowh + j) * HSTR + n0 + ct * 16] = f2bf(v);
        }
      }
  }
  __syncthreads();

  f32x4 acc2[4][2] = {};
#pragma unroll
  for (int ks = 0; ks < 4; ++ks) {
    const int k0 = ks * 32;
    bf16x8 a[4], b[2];
#pragma unroll
    for (int rt = 0; rt < 4; ++rt)
      a[rt] = *reinterpret_cast<const bf16x8*>(&hl[(rt * 16 + lr) * HSTR + k0 + lk]);
#pragma unroll
    for (int ct = 0; ct < 2; ++ct)
      b[ct] = *reinterpret_cast<const bf16x8*>(&PW2T[(size_t)(n0 + ct * 16) * 128 + k0 + lk]);
#pragma unroll
    for (int rt = 0; rt < 4; ++rt)
#pragma unroll
      for (int ct = 0; ct < 2; ++ct)
        acc2[rt][ct] = MFMA16(a[rt], b[ct], acc2[rt][ct]);
  }

  {
    const float b2v0 = b2[n0], b2v1 = b2[n0 + 16];
#pragma unroll
    for (int rt = 0; rt < 4; ++rt)
#pragma unroll
      for (int j = 0; j < 4; ++j) {
        const int row = rt * 16 + rowh + j;
        const int r = r0 + row;
        if (r < NP) {
          out[(size_t)r * 128 + n0]      = h_pair[(size_t)r * 128 + n0]      + acc2[rt][0][j] + b2v0;
          out[(size_t)r * 128 + n0 + 16] = h_pair[(size_t)r * 128 + n0 + 16] + acc2[rt][1][j] + b2v1;
        }
      }
  }
}

// ===================== FALLBACK PATH (round-0 kernels, known-pass) =====================
#define PSI_W1T_OFF 0
#define PSI_W2T_OFF 53248
#define PHI_W1T_OFF 69632
#define PHI_W2T_OFF 102400
#define WS_U16_TOTAL 118784
#define XSTR 424

__global__ void k_prep(const float* __restrict__ psi_w1, const float* __restrict__ psi_w2,
                       const float* __restrict__ phi_w1, const float* __restrict__ phi_w2,
                       u16* __restrict__ ws) {
  int i = blockIdx.x * 256 + threadIdx.x;
  if (i < 128 * 416) {
    int n = i / 416, k = i % 416;
    ws[PSI_W1T_OFF + i] = f2bf(k < 388 ? psi_w1[k * 128 + n] : 0.f);
    return;
  }
  i -= 128 * 416;
  if (i < 128 * 128) {
    int n = i / 128, k = i % 128;
    ws[PSI_W2T_OFF + i] = f2bf(psi_w2[k * 128 + n]);
    return;
  }
  i -= 128 * 128;
  if (i < 128 * 256) {
    int n = i / 256, k = i % 256;
    ws[PHI_W1T_OFF + i] = f2bf(phi_w1[k * 128 + n]);
    return;
  }
  i -= 128 * 256;
  if (i < 128 * 128) {
    int n = i / 128, k = i % 128;
    ws[PHI_W2T_OFF + i] = f2bf(phi_w2[k * 128 + n]);
  }
}

__global__ __launch_bounds__(256, 2) void k_triplet(
    const float* __restrict__ h_pair,
    const int* __restrict__ ivu, const int* __restrict__ iuw, const int* __restrict__ ivw,
    const float* __restrict__ geom,
    const u16* __restrict__ W1T, const u16* __restrict__ W2T,
    const float* __restrict__ b1, const float* __restrict__ b2,
    float* __restrict__ agg) {
  __shared__ __align__(16) u16 xl[64 * XSTR];
  __shared__ __align__(16) u16 hl[64 * HSTR];
  __shared__ int svw[64];

  const int tid = threadIdx.x;
  const int t0 = blockIdx.x * 64;

  {
    const int row = tid >> 2, q = tid & 3;
    const int t = t0 + row;
    const int tc = (t < T_TRIP) ? t : (T_TRIP - 1);
    if (q == 0) svw[row] = (t < T_TRIP) ? ivw[tc] : -1;
    int idx[3];
    idx[0] = ivu[tc]; idx[1] = iuw[tc]; idx[2] = ivw[tc];
#pragma unroll
    for (int s = 0; s < 3; ++s) {
      const float4* src = reinterpret_cast<const float4*>(h_pair + (size_t)idx[s] * 128 + q * 32);
      u16* dst = &xl[row * XSTR + s * 128 + q * 32];
#pragma unroll
      for (int i = 0; i < 8; ++i)
        *reinterpret_cast<ushort4*>(dst + i * 4) = cvt4(src[i]);
    }
  }
  if (tid < 64) {
    const int t = t0 + tid;
    const int tc = (t < T_TRIP) ? t : (T_TRIP - 1);
    const float4 g = reinterpret_cast<const float4*>(geom)[tc];
    u16* dst = &xl[tid * XSTR + 384];
    *reinterpret_cast<ushort4*>(dst) = cvt4(g);
    ushort4 z = {0, 0, 0, 0};
#pragma unroll
    for (int i = 1; i < 8; ++i) *reinterpret_cast<ushort4*>(dst + i * 4) = z;
  }
  __syncthreads();

  const int w = tid >> 6;
  const int l = tid & 63;
  const int lr = l & 15;
  const int lk = (l >> 4) << 3;
  const int n0 = w * 32 + lr;
  const int rowh = (l >> 4) << 2;

  f32x4 acc[4][2] = {};
#pragma unroll 1
  for (int ks = 0; ks < 13; ++ks) {
    const int k0 = ks * 32;
    bf16x8 a[4], b[2];
#pragma unroll
    for (int rt = 0; rt < 4; ++rt)
      a[rt] = *reinterpret_cast<const bf16x8*>(&xl[(rt * 16 + lr) * XSTR + k0 + lk]);
#pragma unroll
    for (int ct = 0; ct < 2; ++ct)
      b[ct] = *reinterpret_cast<const bf16x8*>(&W1T[(size_t)(n0 + ct * 16) * 416 + k0 + lk]);
#pragma unroll
    for (int rt = 0; rt < 4; ++rt)
#pragma unroll
      for (int ct = 0; ct < 2; ++ct)
        acc[rt][ct] = MFMA16(a[rt], b[ct], acc[rt][ct]);
  }

  {
    const float b1v0 = b1[n0], b1v1 = b1[n0 + 16];
#pragma unroll
    for (int rt = 0; rt < 4; ++rt)
#pragma unroll
      for (int ct = 0; ct < 2; ++ct) {
        const float bb = ct ? b1v1 : b1v0;
#pragma unroll
        for (int j = 0; j < 4; ++j) {
          float v = acc[rt][ct][j] + bb;
          v = v / (1.f + __expf(-v));
          hl[(rt * 16 + rowh + j) * HSTR + n0 + ct * 16] = f2bf(v);
        }
      }
  }
  __syncthreads();

  f32x4 acc2[4][2] = {};
#pragma unroll
  for (int ks = 0; ks < 4; ++ks) {
    const int k0 = ks * 32;
    bf16x8 a[4], b[2];
#pragma unroll
    for (int rt = 0; rt < 4; ++rt)
      a[rt] = *reinterpret_cast<const bf16x8*>(&hl[(rt * 16 + lr) * HSTR + k0 + lk]);
#pragma unroll
    for (int ct = 0; ct < 2; ++ct)
      b[ct] = *reinterpret_cast<const bf16x8*>(&W2T[(size_t)(n0 + ct * 16) * 128 + k0 + lk]);
#pragma unroll
    for (int rt = 0; rt < 4; ++rt)
#pragma unroll
      for (int ct = 0; ct < 2; ++ct)
        acc2[rt][ct] = MFMA16(a[rt], b[ct], acc2[rt][ct]);
  }

  {
    const float b2v0 = b2[n0], b2v1 = b2[n0 + 16];
#pragma unroll
    for (int rt = 0; rt < 4; ++rt)
#pragma unroll
      for (int j = 0; j < 4; ++j) {
        const int row = rt * 16 + rowh + j;
        const int dst = svw[row];
        if (dst >= 0) {
          unsafeAtomicAdd(&agg[(size_t)dst * 128 + n0], acc2[rt][0][j] + b2v0);
          unsafeAtomicAdd(&agg[(size_t)dst * 128 + n0 + 16], acc2[rt][1][j] + b2v1);
        }
      }
  }
}

__global__ __launch_bounds__(256, 2) void k_pair(
    const float* __restrict__ h_pair,
    const u16* __restrict__ W1T, const u16* __restrict__ W2T,
    const float* __restrict__ b1, const float* __restrict__ b2,
    float* __restrict__ out) {
  __shared__ __align__(16) u16 xl[64 * X2STR];
  __shared__ __align__(16) u16 hl[64 * HSTR];

  const int tid = threadIdx.x;
  const int r0 = blockIdx.x * 64;

  {
    const int row = tid >> 2, q = tid & 3;
    const int r = r0 + row;
    const int rc = (r < NP) ? r : (NP - 1);
    const float4* s1 = reinterpret_cast<const float4*>(h_pair + (size_t)rc * 128 + q * 32);
    const float4* s2 = reinterpret_cast<const float4*>(out + (size_t)rc * 128 + q * 32);
    u16* d1 = &xl[row * X2STR + q * 32];
    u16* d2 = &xl[row * X2STR + 128 + q * 32];
#pragma unroll
    for (int i = 0; i < 8; ++i) {
      *reinterpret_cast<ushort4*>(d1 + i * 4) = cvt4(s1[i]);
      *reinterpret_cast<ushort4*>(d2 + i * 4) = cvt4(s2[i]);
    }
  }
  __syncthreads();

  const int w = tid >> 6;
  const int l = tid & 63;
  const int lr = l & 15;
  const int lk = (l >> 4) << 3;
  const int n0 = w * 32 + lr;
  const int rowh = (l >> 4) << 2;

  f32x4 acc[4][2] = {};
#pragma unroll 1
  for (int ks = 0; ks < 8; ++ks) {
    const int k0 = ks * 32;
    bf16x8 a[4], b[2];
#pragma unroll
    for (int rt = 0; rt < 4; ++rt)
      a[rt] = *reinterpret_cast<const bf16x8*>(&xl[(rt * 16 + lr) * X2STR + k0 + lk]);
#pragma unroll
    for (int ct = 0; ct < 2; ++ct)
      b[ct] = *reinterpret_cast<const bf16x8*>(&W1T[(size_t)(n0 + ct * 16) * 256 + k0 + lk]);
#pragma unroll
    for (int rt = 0; rt < 4; ++rt)
#pragma unroll
      for (int ct = 0; ct < 2; ++ct)
        acc[rt][ct] = MFMA16(a[rt], b[ct], acc[rt][ct]);
  }

  {
    const float b1v0 = b1[n0], b1v1 = b1[n0 + 16];
#pragma unroll
    for (int rt = 0; rt < 4; ++rt)
#pragma unroll
      for (int ct = 0; ct < 2; ++ct) {
        const float bb = ct ? b1v1 : b1v0;
#pragma unroll
        for (int j = 0; j < 4; ++j) {
          float v = acc[rt][ct][j] + bb;
          v = v / (1.f + __expf(-v));
          hl[(rt * 16 + rowh + j) * HSTR + n0 + ct * 16] = f2bf(v);
        }
      }
  }
  __syncthreads();

  f32x4 acc2[4][2] = {};
#pragma unroll
  for (int ks = 0; ks < 4; ++ks) {
    const int k0 = ks * 32;
    bf16x8 a[4], b[2];
#pragma unroll
    for (int rt = 0; rt < 4; ++rt)
      a[rt] = *reinterpret_cast<const bf16x8*>(&hl[(rt * 16 + lr) * HSTR + k0 + lk]);
#pragma unroll
    for (int ct = 0; ct < 2; ++ct)
      b[ct] = *reinterpret_cast<const bf16x8*>(&W2T[(size_t)(n0 + ct * 16) * 128 + k0 + lk]);
#pragma unroll
    for (int rt = 0; rt < 4; ++rt)
#pragma unroll
      for (int ct = 0; ct < 2; ++ct)
        acc2[rt][ct] = MFMA16(a[rt], b[ct], acc2[rt][ct]);
  }

  {
    const float b2v0 = b2[n0], b2v1 = b2[n0 + 16];
#pragma unroll
    for (int rt = 0; rt < 4; ++rt)
#pragma unroll
      for (int j = 0; j < 4; ++j) {
        const int row = rt * 16 + rowh + j;
        const int r = r0 + row;
        if (r < NP) {
          out[(size_t)r * 128 + n0]      = h_pair[(size_t)r * 128 + n0]      + acc2[rt][0][j] + b2v0;
          out[(size_t)r * 128 + n0 + 16] = h_pair[(size_t)r * 128 + n0 + 16] + acc2[rt][1][j] + b2v1;
        }
      }
  }
}

extern "C" void kernel_launch(void* const* d_in, const int* in_sizes, int n_in,
                              void* d_out, int out_size, void* d_ws, size_t ws_size,
                              hipStream_t stream) {
  const float* h_pair = (const float*)d_in[0];
  const int* ivu = (const int*)d_in[1];
  const int* iuw = (const int*)d_in[2];
  const int* ivw = (const int*)d_in[3];
  const float* geom = (const float*)d_in[4];
  const float* psi_w1 = (const float*)d_in[5];
  const float* psi_b1 = (const float*)d_in[6];
  const float* psi_w2 = (const float*)d_in[7];
  const float* psi_b2 = (const float*)d_in[8];
  const float* phi_w1 = (const float*)d_in[9];
  const float* phi_b1 = (const float*)d_in[10];
  const float* phi_w2 = (const float*)d_in[11];
  const float* phi_b2 = (const float*)d_in[12];

  float* out = (float*)d_out;
  u16* ws = (u16*)d_ws;

  if (ws_size >= WS_NEED_BYTES) {
    // ---- fast path ----
    k_prep_fast<<<450, 256, 0, stream>>>(psi_w1, psi_w2, phi_w1, phi_w2, ws);
    k_hconv<<<6250, 256, 0, stream>>>(h_pair, ws + FP_H, ws + FP_AGG);
    k_triplet_fast<<<768, 256, 0, stream>>>(
        ws + FP_H, ivu, iuw, ivw, geom,
        ws + FP_W1A, ws + FP_W1B, ws + FP_W1C,
        reinterpret_cast<const float*>(ws + FP_W1D), ws + FP_W2,
        psi_b1, psi_b2, ws + FP_AGG);
    k_pair_fast<<<(NP + 63) / 64, 256, 0, stream>>>(
        h_pair, ws + FP_H, ws + FP_AGG,
        ws + FP_PW1, ws + FP_PW2, phi_b1, phi_b2, out);
  } else {
    // ---- fallback (round-0) ----
    hipMemsetAsync(d_out, 0, (size_t)out_size * sizeof(float), stream);
    k_prep<<<(WS_U16_TOTAL + 255) / 256, 256, 0, stream>>>(psi_w1, psi_w2, phi_w1, phi_w2, ws);
    k_triplet<<<(T_TRIP + 63) / 64, 256, 0, stream>>>(
        h_pair, ivu, iuw, ivw, geom,
        ws + PSI_W1T_OFF, ws + PSI_W2T_OFF, psi_b1, psi_b2, out);
    k_pair<<<(NP + 63) / 64, 256, 0, stream>>>(
        h_pair, ws + PHI_W1T_OFF, ws + PHI_W2T_OFF, phi_b1, phi_b2, out);
  }
}